// Round 12
// baseline (128.726 us; speedup 1.0000x reference)
//
#include <hip/hip_runtime.h>

typedef unsigned short u16;
typedef __attribute__((ext_vector_type(8))) __bf16 bf16x8;
typedef __attribute__((ext_vector_type(4))) float f32x4;
typedef __attribute__((ext_vector_type(16))) float f32x16;
typedef __attribute__((ext_vector_type(8))) u16 u16x8;
typedef __attribute__((ext_vector_type(4))) u16 u16x4;
typedef __attribute__((ext_vector_type(4))) unsigned u32x4;

#define AS1 __attribute__((address_space(1)))
#define AS3 __attribute__((address_space(3)))

#if __has_builtin(__builtin_amdgcn_exp2f)
#define EXP2(x) __builtin_amdgcn_exp2f(x)
#else
#define EXP2(x) exp2f(x)
#endif

// ---------- helpers ----------
__device__ __forceinline__ u16 f2bf(float f) {
  union { float f; unsigned u; } cv; cv.f = f;
  return (u16)((cv.u + 0x7FFFu + ((cv.u >> 16) & 1u)) >> 16);
}

__device__ __forceinline__ void gload16(const void* g, void* l) {
  __builtin_amdgcn_global_load_lds((AS1 const void*)g, (AS3 void*)l, 16, 0, 0);
}

__device__ __forceinline__ unsigned cvtpk(float lo, float hi_) {
  unsigned d;
  asm("v_cvt_pk_bf16_f32 %0, %1, %2" : "=v"(d) : "v"(lo), "v"(hi_));
  return d;
}

// LDS tile [64 rows][64 u16], XOR-swizzled 16B chunks.
__device__ __forceinline__ int lds_off(int row, int chunk) {
  return row * 64 + ((chunk ^ (row & 7)) << 3);
}

// ---------- fp32 -> bf16 convert ----------
__global__ void cvt_kernel(const float* __restrict__ s0, u16* __restrict__ d0, int n0,
                           const float* __restrict__ s1, u16* __restrict__ d1, int n1,
                           const float* __restrict__ s2, u16* __restrict__ d2, int n2,
                           const float* __restrict__ s3, u16* __restrict__ d3, int n3,
                           const float* __restrict__ s4, u16* __restrict__ d4, int n4,
                           const float* __restrict__ s5, u16* __restrict__ d5, int n5) {
  const float* s; u16* d; int n;
  switch (blockIdx.y) {
    case 0: s = s0; d = d0; n = n0; break;
    case 1: s = s1; d = d1; n = n1; break;
    case 2: s = s2; d = d2; n = n2; break;
    case 3: s = s3; d = d3; n = n3; break;
    case 4: s = s4; d = d4; n = n4; break;
    default: s = s5; d = d5; n = n5; break;
  }
  const int stride = gridDim.x * blockDim.x;
  for (int i = blockIdx.x * blockDim.x + threadIdx.x; i < n; i += stride) {
    const float4* p = (const float4*)(s + (size_t)i * 8);
    float4 a = p[0], b = p[1];
    u16x8 r;
    r[0] = f2bf(a.x); r[1] = f2bf(a.y); r[2] = f2bf(a.z); r[3] = f2bf(a.w);
    r[4] = f2bf(b.x); r[5] = f2bf(b.y); r[6] = f2bf(b.z); r[7] = f2bf(b.w);
    *(u16x8*)(d + (size_t)i * 8) = r;
  }
}

// ---------- shared GEMM mainloop: C[128x128] += A[128xK] * B[128xK]^T ----------
__device__ __forceinline__ void gemm_core(const u16* __restrict__ A,
                                          const u16* __restrict__ Bm,
                                          u16* As, u16* Bs,
                                          int rowBase, int colBase,
                                          f32x4 acc[4][4]) {
  const int tid = threadIdx.x;
  const int lane = tid & 63, w = tid >> 6;
  const int wr = w >> 1, wc = w & 1;
  const int l15 = lane & 15, g = lane >> 4;

  for (int kt = 0; kt < 1024; kt += 32) {
    __syncthreads();
#pragma unroll
    for (int it = 0; it < 2; ++it) {
      int e = it * 256 + tid;
      int r = e >> 2, kc = (e & 3) << 3;
      gload16(A + (((size_t)(rowBase + r)) << 10) + kt + kc, As + e * 8);
      gload16(Bm + (((size_t)(colBase + r)) << 10) + kt + kc, Bs + e * 8);
    }
    __syncthreads();
    bf16x8 a[4], b[4];
#pragma unroll
    for (int mt = 0; mt < 4; ++mt)
      a[mt] = *(const bf16x8*)(As + (wr * 64 + mt * 16 + l15) * 32 + g * 8);
#pragma unroll
    for (int nt = 0; nt < 4; ++nt)
      b[nt] = *(const bf16x8*)(Bs + (wc * 64 + nt * 16 + l15) * 32 + g * 8);
#pragma unroll
    for (int mt = 0; mt < 4; ++mt)
#pragma unroll
      for (int nt = 0; nt < 4; ++nt)
        acc[mt][nt] = __builtin_amdgcn_mfma_f32_16x16x32_bf16(a[mt], b[nt], acc[mt][nt], 0, 0, 0);
  }
}

// ---------- fused Q/K/V projections ----------
// z=0: Qp = (qb*wqb^T + b_q) * (0.125*log2e)
// z=1: Kp = kb*wkb^T + b_k
// z=2: VT = vb*wkb^T + b_k, stored transposed as [b][h][d][s'] with
//      s' = s with bits 2,3 swapped (pi-permutation): bakes the PV fragment
//      permutation into memory so flash_attn needs no cross-lane P exchange.
__global__ __launch_bounds__(256)
void proj_gemm(const u16* __restrict__ qb, const u16* __restrict__ kb, const u16* __restrict__ vb,
               const u16* __restrict__ wqb, const u16* __restrict__ wkb,
               const float* __restrict__ b_q, const float* __restrict__ b_k,
               u16* __restrict__ Qp, u16* __restrict__ Kp, u16* __restrict__ VTp) {
  __shared__ __align__(16) u16 As[128 * 32];
  __shared__ __align__(16) u16 Bs[128 * 32];

  const u16* A; const u16* Bm; const float* bias; u16* C; int mode;
  float scale = 1.0f;
  if (blockIdx.z == 0)      { A = qb; Bm = wqb; bias = b_q; C = Qp;  mode = 0; scale = 0.18033688011112042f; }
  else if (blockIdx.z == 1) { A = kb; Bm = wkb; bias = b_k; C = Kp;  mode = 0; }
  else                      { A = vb; Bm = wkb; bias = b_k; C = VTp; mode = 1; }

  const int rowBase = blockIdx.x * 128;
  const int colBase = blockIdx.y * 128;
  f32x4 acc[4][4];
  const f32x4 z4 = {0.f, 0.f, 0.f, 0.f};
#pragma unroll
  for (int i = 0; i < 4; ++i)
#pragma unroll
    for (int j = 0; j < 4; ++j) acc[i][j] = z4;

  gemm_core(A, Bm, As, Bs, rowBase, colBase, acc);

  const int tid = threadIdx.x;
  const int lane = tid & 63, w = tid >> 6;
  const int wr = w >> 1, wc = w & 1;
  const int l15 = lane & 15, g = lane >> 4;
#pragma unroll
  for (int mt = 0; mt < 4; ++mt)
#pragma unroll
    for (int nt = 0; nt < 4; ++nt) {
      int col = colBase + wc * 64 + nt * 16 + l15;
      float bia = bias[col];
#pragma unroll
      for (int r = 0; r < 4; ++r) {
        int row = rowBase + wr * 64 + mt * 16 + g * 4 + r;
        float val = (acc[mt][nt][r] + bia) * scale;
        if (mode == 0) {
          C[(((size_t)row) << 10) + col] = f2bf(val);
        } else {
          int bb = row >> 11, s = row & 2047;
          // swap bits 2 and 3 of s (involution, 16-block-local)
          int s2 = s ^ ((((s >> 2) ^ (s >> 3)) & 1) * 12);
          int hh = col >> 6, d = col & 63;
          C[((((size_t)(bb * 16 + hh)) << 6) + d) * 2048 + s2] = f2bf(val);
        }
      }
    }
}

// ---------- output projection: 64x128 tiles, 2 blocks/CU ----------
__global__ __launch_bounds__(256)
void out_gemm(const u16* __restrict__ AO, const u16* __restrict__ wob,
              const float* __restrict__ b_o, float* __restrict__ C) {
  __shared__ __align__(16) u16 As[64 * 32];
  __shared__ __align__(16) u16 Bs[128 * 32];
  const int rowBase = blockIdx.x * 64;
  const int colBase = blockIdx.y * 128;

  const int tid = threadIdx.x;
  const int lane = tid & 63, w = tid >> 6;
  const int wr = w >> 1, wc = w & 1;
  const int l15 = lane & 15, g = lane >> 4;

  f32x4 acc[2][4];
  const f32x4 z4 = {0.f, 0.f, 0.f, 0.f};
#pragma unroll
  for (int i = 0; i < 2; ++i)
#pragma unroll
    for (int j = 0; j < 4; ++j) acc[i][j] = z4;

  for (int kt = 0; kt < 1024; kt += 32) {
    __syncthreads();
    {
      // A: 64 rows x 4 chunks = 256 chunk-slots, 1 per thread
      int r = tid >> 2, kc = (tid & 3) << 3;
      gload16(AO + (((size_t)(rowBase + r)) << 10) + kt + kc, As + tid * 8);
    }
#pragma unroll
    for (int it = 0; it < 2; ++it) {
      int e = it * 256 + tid;
      int r = e >> 2, kc = (e & 3) << 3;
      gload16(wob + (((size_t)(colBase + r)) << 10) + kt + kc, Bs + e * 8);
    }
    __syncthreads();
    bf16x8 a[2], b[4];
#pragma unroll
    for (int mt = 0; mt < 2; ++mt)
      a[mt] = *(const bf16x8*)(As + (wr * 32 + mt * 16 + l15) * 32 + g * 8);
#pragma unroll
    for (int nt = 0; nt < 4; ++nt)
      b[nt] = *(const bf16x8*)(Bs + (wc * 64 + nt * 16 + l15) * 32 + g * 8);
#pragma unroll
    for (int mt = 0; mt < 2; ++mt)
#pragma unroll
      for (int nt = 0; nt < 4; ++nt)
        acc[mt][nt] = __builtin_amdgcn_mfma_f32_16x16x32_bf16(a[mt], b[nt], acc[mt][nt], 0, 0, 0);
  }

#pragma unroll
  for (int mt = 0; mt < 2; ++mt)
#pragma unroll
    for (int nt = 0; nt < 4; ++nt) {
      int col = colBase + wc * 64 + nt * 16 + l15;
      float bia = b_o[col];
#pragma unroll
      for (int r = 0; r < 4; ++r) {
        int row = rowBase + wr * 32 + mt * 16 + g * 4 + r;
        C[(((size_t)row) << 10) + col] = acc[mt][nt][r] + bia;
      }
    }
}

// ---------- flash attention (R8/R11 structure, ONE barrier per tile-iter) ----------
// Grid (16, 32): 16 q-blocks of 128, 32 (b,h). 256 thr = 4 waves, wave owns 32 q.
// Hazard proof for single-barrier double-buffer:
//  WAR: stage(t+1, cb^1) issued after top-barrier of t; all waves finished
//       body t-1 (the last reads of cb^1) before that barrier.  OK
//  Visibility: each wave drains its OWN vmcnt(0) before the top barrier of
//       t+1, so every wave's stage(t+1) LDS writes have landed before any
//       wave reads them in body t+1.  OK
template <int KS4>
__device__ __forceinline__ void pv_step(const f32x16& sv, int hi, const u16* Vt, int l31,
                                        f32x16& o0, f32x16& o1) {
  constexpr int B = (KS4 & 1) * 8;
  u32x4 pd;
  pd[0] = cvtpk(sv[B + 0], sv[B + 1]);
  pd[1] = cvtpk(sv[B + 2], sv[B + 3]);
  pd[2] = cvtpk(sv[B + 4], sv[B + 5]);
  pd[3] = cvtpk(sv[B + 6], sv[B + 7]);
  bf16x8 pfrag = __builtin_bit_cast(bf16x8, pd);
  bf16x8 av0 = *(const bf16x8*)(Vt + lds_off(l31, 2 * KS4 + hi));
  bf16x8 av1 = *(const bf16x8*)(Vt + lds_off(32 + l31, 2 * KS4 + hi));
  o0 = __builtin_amdgcn_mfma_f32_32x32x16_bf16(av0, pfrag, o0, 0, 0, 0);
  o1 = __builtin_amdgcn_mfma_f32_32x32x16_bf16(av1, pfrag, o1, 0, 0, 0);
}

__global__ __launch_bounds__(256, 2)
void flash_attn(const u16* __restrict__ Qp, const u16* __restrict__ Kp,
                const u16* __restrict__ VT, u16* __restrict__ AO) {
  __shared__ __align__(16) u16 KB[2][64 * 64];
  __shared__ __align__(16) u16 VB[2][64 * 64];

  const int tid = threadIdx.x;
  const int lane = tid & 63;
  const int w = tid >> 6;       // 0..3
  const int l31 = lane & 31;
  const int hi = lane >> 5;

  // bijective XCD swizzle (nwg=512, 8 XCDs -> 64 contiguous wgs per XCD = 4 bh)
  const int flat = blockIdx.x + (blockIdx.y << 4);
  const int wgid = (flat & 7) * 64 + (flat >> 3);
  const int bh = wgid >> 4;
  const int qblk = wgid & 15;
  const int b = bh >> 4, h = bh & 15;
  const int q = qblk * 128 + w * 32 + l31;

  const size_t qrow = ((size_t)(b * 2048 + q)) << 10;
  const u16* Kbase = Kp + (((size_t)(b * 2048)) << 10) + h * 64;
  const u16* Vbase = VT + (((size_t)(bh * 64)) << 11);

  // staging: LDS dest linear, global source pre-swizzled (rule #21).
  const int sr = tid >> 3;
  const int sc = (tid & 7) ^ (sr & 7);

  auto stage = [&](int tt, int buf) {
    const int kv0 = tt * 64;
    gload16(Kbase + (((size_t)(kv0 + sr)) << 10) + sc * 8, &KB[buf][tid * 8]);
    gload16(Kbase + (((size_t)(kv0 + 32 + sr)) << 10) + sc * 8, &KB[buf][2048 + tid * 8]);
    gload16(Vbase + sr * 2048 + kv0 + sc * 8, &VB[buf][tid * 8]);
    gload16(Vbase + (32 + sr) * 2048 + kv0 + sc * 8, &VB[buf][2048 + tid * 8]);
  };

  stage(0, 0);

  // Q fragments (B-operand): d = ks*16 + hi*8 + j
  bf16x8 qf[4];
#pragma unroll
  for (int ks = 0; ks < 4; ++ks)
    qf[ks] = *(const bf16x8*)(Qp + qrow + h * 64 + ks * 16 + hi * 8);

  float m = -1e30f, l = 0.f;
  f32x16 o0, o1;
#pragma unroll
  for (int i = 0; i < 16; ++i) { o0[i] = 0.f; o1[i] = 0.f; }

  for (int t = 0; t < 32; ++t) {
    const int cb = t & 1;
    // single sync point: own-loads drained, then block rendezvous
    asm volatile("s_waitcnt vmcnt(0)" ::: "memory");
    __builtin_amdgcn_sched_barrier(0);
    __builtin_amdgcn_s_barrier();
    __builtin_amdgcn_sched_barrier(0);
    if (t < 31) stage(t + 1, cb ^ 1);

    const u16* Kt = &KB[cb][0];
    const u16* Vt = &VB[cb][0];

    // S^T tile: rows kv (two 32-subtiles), cols q
    f32x16 s0, s1;
#pragma unroll
    for (int i = 0; i < 16; ++i) { s0[i] = 0.f; s1[i] = 0.f; }
#pragma unroll
    for (int ks = 0; ks < 4; ++ks) {
      bf16x8 ak0 = *(const bf16x8*)(Kt + lds_off(l31, 2 * ks + hi));
      bf16x8 ak1 = *(const bf16x8*)(Kt + lds_off(32 + l31, 2 * ks + hi));
      s0 = __builtin_amdgcn_mfma_f32_32x32x16_bf16(ak0, qf[ks], s0, 0, 0, 0);
      s1 = __builtin_amdgcn_mfma_f32_32x32x16_bf16(ak1, qf[ks], s1, 0, 0, 0);
    }

    // in-lane max over the lane's 32 kv values (log2-domain scores)
    f32x16 mm;
#pragma unroll
    for (int i = 0; i < 16; ++i) mm[i] = fmaxf(s0[i], s1[i]);
#pragma unroll
    for (int i = 0; i < 8; ++i) mm[i] = fmaxf(mm[i], mm[i + 8]);
#pragma unroll
    for (int i = 0; i < 4; ++i) mm[i] = fmaxf(mm[i], mm[i + 4]);
    float pm = fmaxf(fmaxf(mm[0], mm[1]), fmaxf(mm[2], mm[3]));
    pm = fmaxf(pm, __shfl_xor(pm, 32));

    // defer-max (T13)
    if (!__all(pm - m <= 11.0f)) {
      float mn = fmaxf(m, pm);
      float fr = EXP2(m - mn);
      m = mn;
      l *= fr;
#pragma unroll
      for (int i = 0; i < 16; ++i) { o0[i] *= fr; o1[i] *= fr; }
    }

    // p = exp2(s - m)
#pragma unroll
    for (int i = 0; i < 16; ++i) {
      s0[i] = EXP2(s0[i] - m);
      s1[i] = EXP2(s1[i] - m);
    }
    // row sum
#pragma unroll
    for (int i = 0; i < 16; ++i) mm[i] = s0[i] + s1[i];
#pragma unroll
    for (int i = 0; i < 8; ++i) mm[i] += mm[i + 8];
#pragma unroll
    for (int i = 0; i < 4; ++i) mm[i] += mm[i + 4];
    float ps = (mm[0] + mm[1]) + (mm[2] + mm[3]);
    ps += __shfl_xor(ps, 32);
    l += ps;

    // PV: O^T += V'^T * P  (V' pi-permuted in memory; P from own regs)
    pv_step<0>(s0, hi, Vt, l31, o0, o1);
    pv_step<1>(s0, hi, Vt, l31, o0, o1);
    pv_step<2>(s1, hi, Vt, l31, o0, o1);
    pv_step<3>(s1, hi, Vt, l31, o0, o1);
  }

  const float linv = 1.0f / l;
#pragma unroll
  for (int dt = 0; dt < 2; ++dt) {
    const f32x16& oo = dt ? o1 : o0;
#pragma unroll
    for (int g = 0; g < 4; ++g) {
      u16x4 pk;
#pragma unroll
      for (int r = 0; r < 4; ++r) pk[r] = f2bf(oo[g * 4 + r] * linv);
      const int d = dt * 32 + g * 8 + hi * 4;
      *(u16x4*)(AO + qrow + h * 64 + d) = pk;
    }
  }
}

// ---------- launch ----------
extern "C" void kernel_launch(void* const* d_in, const int* in_sizes, int n_in,
                              void* d_out, int out_size, void* d_ws, size_t ws_size,
                              hipStream_t stream) {
  const float* q   = (const float*)d_in[1];
  const float* k   = (const float*)d_in[2];
  const float* v   = (const float*)d_in[3];
  const float* w_q = (const float*)d_in[5];
  const float* b_q = (const float*)d_in[6];
  const float* w_k = (const float*)d_in[7];
  const float* b_k = (const float*)d_in[8];
  const float* w_o = (const float*)d_in[11];
  const float* b_o = (const float*)d_in[12];
  float* out = (float*)d_out;

  u16* qb  = (u16*)d_ws;
  u16* kb  = qb  + 4194304;
  u16* vb  = kb  + 4194304;
  u16* wqb = vb  + 4194304;
  u16* wkb = wqb + 1048576;
  u16* wob = wkb + 1048576;
  u16* Qp  = wob + 1048576;
  u16* Kp  = Qp  + 4194304;
  u16* VTp = Kp  + 4194304;
  u16* AO  = qb;  // alias: qb dead after proj_gemm

  cvt_kernel<<<dim3(512, 6, 1), 256, 0, stream>>>(
      q, qb, 524288, k, kb, 524288, v, vb, 524288,
      w_q, wqb, 131072, w_k, wkb, 131072, w_o, wob, 131072);

  proj_gemm<<<dim3(32, 8, 3), 256, 0, stream>>>(qb, kb, vb, wqb, wkb, b_q, b_k, Qp, Kp, VTp);

  flash_attn<<<dim3(16, 32, 1), 256, 0, stream>>>(Qp, Kp, VTp, AO);

  out_gemm<<<dim3(64, 8, 1), 256, 0, stream>>>(AO, wob, b_o, out);
}

// Round 13
// 125.813 us; speedup vs baseline: 1.0232x; 1.0232x over previous
//
#include <hip/hip_runtime.h>

typedef unsigned short u16;
typedef __attribute__((ext_vector_type(8))) __bf16 bf16x8;
typedef __attribute__((ext_vector_type(4))) float f32x4;
typedef __attribute__((ext_vector_type(16))) float f32x16;
typedef __attribute__((ext_vector_type(8))) u16 u16x8;
typedef __attribute__((ext_vector_type(4))) u16 u16x4;
typedef __attribute__((ext_vector_type(4))) unsigned u32x4;

#define AS1 __attribute__((address_space(1)))
#define AS3 __attribute__((address_space(3)))

#if __has_builtin(__builtin_amdgcn_exp2f)
#define EXP2(x) __builtin_amdgcn_exp2f(x)
#else
#define EXP2(x) exp2f(x)
#endif

// ---------- helpers ----------
__device__ __forceinline__ u16 f2bf(float f) {
  union { float f; unsigned u; } cv; cv.f = f;
  return (u16)((cv.u + 0x7FFFu + ((cv.u >> 16) & 1u)) >> 16);
}

__device__ __forceinline__ void gload16(const void* g, void* l) {
  __builtin_amdgcn_global_load_lds((AS1 const void*)g, (AS3 void*)l, 16, 0, 0);
}

__device__ __forceinline__ unsigned cvtpk(float lo, float hi_) {
  unsigned d;
  asm("v_cvt_pk_bf16_f32 %0, %1, %2" : "=v"(d) : "v"(lo), "v"(hi_));
  return d;
}

// LDS tile [64 rows][64 u16], XOR-swizzled 16B chunks.
__device__ __forceinline__ int lds_off(int row, int chunk) {
  return row * 64 + ((chunk ^ (row & 7)) << 3);
}

// ---------- fp32 -> bf16 convert ----------
__global__ void cvt_kernel(const float* __restrict__ s0, u16* __restrict__ d0, int n0,
                           const float* __restrict__ s1, u16* __restrict__ d1, int n1,
                           const float* __restrict__ s2, u16* __restrict__ d2, int n2,
                           const float* __restrict__ s3, u16* __restrict__ d3, int n3,
                           const float* __restrict__ s4, u16* __restrict__ d4, int n4,
                           const float* __restrict__ s5, u16* __restrict__ d5, int n5) {
  const float* s; u16* d; int n;
  switch (blockIdx.y) {
    case 0: s = s0; d = d0; n = n0; break;
    case 1: s = s1; d = d1; n = n1; break;
    case 2: s = s2; d = d2; n = n2; break;
    case 3: s = s3; d = d3; n = n3; break;
    case 4: s = s4; d = d4; n = n4; break;
    default: s = s5; d = d5; n = n5; break;
  }
  const int stride = gridDim.x * blockDim.x;
  for (int i = blockIdx.x * blockDim.x + threadIdx.x; i < n; i += stride) {
    const float4* p = (const float4*)(s + (size_t)i * 8);
    float4 a = p[0], b = p[1];
    u16x8 r;
    r[0] = f2bf(a.x); r[1] = f2bf(a.y); r[2] = f2bf(a.z); r[3] = f2bf(a.w);
    r[4] = f2bf(b.x); r[5] = f2bf(b.y); r[6] = f2bf(b.z); r[7] = f2bf(b.w);
    *(u16x8*)(d + (size_t)i * 8) = r;
  }
}

// ---------- shared GEMM mainloop: C[128x128] += A[128xK] * B[128xK]^T ----------
__device__ __forceinline__ void gemm_core(const u16* __restrict__ A,
                                          const u16* __restrict__ Bm,
                                          u16* As, u16* Bs,
                                          int rowBase, int colBase,
                                          f32x4 acc[4][4]) {
  const int tid = threadIdx.x;
  const int lane = tid & 63, w = tid >> 6;
  const int wr = w >> 1, wc = w & 1;
  const int l15 = lane & 15, g = lane >> 4;

  for (int kt = 0; kt < 1024; kt += 32) {
    __syncthreads();
#pragma unroll
    for (int it = 0; it < 2; ++it) {
      int e = it * 256 + tid;
      int r = e >> 2, kc = (e & 3) << 3;
      gload16(A + (((size_t)(rowBase + r)) << 10) + kt + kc, As + e * 8);
      gload16(Bm + (((size_t)(colBase + r)) << 10) + kt + kc, Bs + e * 8);
    }
    __syncthreads();
    bf16x8 a[4], b[4];
#pragma unroll
    for (int mt = 0; mt < 4; ++mt)
      a[mt] = *(const bf16x8*)(As + (wr * 64 + mt * 16 + l15) * 32 + g * 8);
#pragma unroll
    for (int nt = 0; nt < 4; ++nt)
      b[nt] = *(const bf16x8*)(Bs + (wc * 64 + nt * 16 + l15) * 32 + g * 8);
#pragma unroll
    for (int mt = 0; mt < 4; ++mt)
#pragma unroll
      for (int nt = 0; nt < 4; ++nt)
        acc[mt][nt] = __builtin_amdgcn_mfma_f32_16x16x32_bf16(a[mt], b[nt], acc[mt][nt], 0, 0, 0);
  }
}

// ---------- fused Q/K/V projections ----------
// z=0: Qp = (qb*wqb^T + b_q) * (0.125*log2e)
// z=1: Kp = kb*wkb^T + b_k
// z=2: VT = vb*wkb^T + b_k, stored transposed as [b][h][d][s'] with
//      s' = s with bits 2,3 swapped (pi-permutation): bakes the PV fragment
//      permutation into memory so flash_attn needs no cross-lane P exchange.
__global__ __launch_bounds__(256)
void proj_gemm(const u16* __restrict__ qb, const u16* __restrict__ kb, const u16* __restrict__ vb,
               const u16* __restrict__ wqb, const u16* __restrict__ wkb,
               const float* __restrict__ b_q, const float* __restrict__ b_k,
               u16* __restrict__ Qp, u16* __restrict__ Kp, u16* __restrict__ VTp) {
  __shared__ __align__(16) u16 As[128 * 32];
  __shared__ __align__(16) u16 Bs[128 * 32];

  const u16* A; const u16* Bm; const float* bias; u16* C; int mode;
  float scale = 1.0f;
  if (blockIdx.z == 0)      { A = qb; Bm = wqb; bias = b_q; C = Qp;  mode = 0; scale = 0.18033688011112042f; }
  else if (blockIdx.z == 1) { A = kb; Bm = wkb; bias = b_k; C = Kp;  mode = 0; }
  else                      { A = vb; Bm = wkb; bias = b_k; C = VTp; mode = 1; }

  const int rowBase = blockIdx.x * 128;
  const int colBase = blockIdx.y * 128;
  f32x4 acc[4][4];
  const f32x4 z4 = {0.f, 0.f, 0.f, 0.f};
#pragma unroll
  for (int i = 0; i < 4; ++i)
#pragma unroll
    for (int j = 0; j < 4; ++j) acc[i][j] = z4;

  gemm_core(A, Bm, As, Bs, rowBase, colBase, acc);

  const int tid = threadIdx.x;
  const int lane = tid & 63, w = tid >> 6;
  const int wr = w >> 1, wc = w & 1;
  const int l15 = lane & 15, g = lane >> 4;
#pragma unroll
  for (int mt = 0; mt < 4; ++mt)
#pragma unroll
    for (int nt = 0; nt < 4; ++nt) {
      int col = colBase + wc * 64 + nt * 16 + l15;
      float bia = bias[col];
#pragma unroll
      for (int r = 0; r < 4; ++r) {
        int row = rowBase + wr * 64 + mt * 16 + g * 4 + r;
        float val = (acc[mt][nt][r] + bia) * scale;
        if (mode == 0) {
          C[(((size_t)row) << 10) + col] = f2bf(val);
        } else {
          int bb = row >> 11, s = row & 2047;
          // swap bits 2 and 3 of s (involution, 16-block-local)
          int s2 = s ^ ((((s >> 2) ^ (s >> 3)) & 1) * 12);
          int hh = col >> 6, d = col & 63;
          C[((((size_t)(bb * 16 + hh)) << 6) + d) * 2048 + s2] = f2bf(val);
        }
      }
    }
}

// ---------- output projection: 64x128 tiles, 2 blocks/CU ----------
__global__ __launch_bounds__(256)
void out_gemm(const u16* __restrict__ AO, const u16* __restrict__ wob,
              const float* __restrict__ b_o, float* __restrict__ C) {
  __shared__ __align__(16) u16 As[64 * 32];
  __shared__ __align__(16) u16 Bs[128 * 32];
  const int rowBase = blockIdx.x * 64;
  const int colBase = blockIdx.y * 128;

  const int tid = threadIdx.x;
  const int lane = tid & 63, w = tid >> 6;
  const int wr = w >> 1, wc = w & 1;
  const int l15 = lane & 15, g = lane >> 4;

  f32x4 acc[2][4];
  const f32x4 z4 = {0.f, 0.f, 0.f, 0.f};
#pragma unroll
  for (int i = 0; i < 2; ++i)
#pragma unroll
    for (int j = 0; j < 4; ++j) acc[i][j] = z4;

  for (int kt = 0; kt < 1024; kt += 32) {
    __syncthreads();
    {
      int r = tid >> 2, kc = (tid & 3) << 3;
      gload16(AO + (((size_t)(rowBase + r)) << 10) + kt + kc, As + tid * 8);
    }
#pragma unroll
    for (int it = 0; it < 2; ++it) {
      int e = it * 256 + tid;
      int r = e >> 2, kc = (e & 3) << 3;
      gload16(wob + (((size_t)(colBase + r)) << 10) + kt + kc, Bs + e * 8);
    }
    __syncthreads();
    bf16x8 a[2], b[4];
#pragma unroll
    for (int mt = 0; mt < 2; ++mt)
      a[mt] = *(const bf16x8*)(As + (wr * 32 + mt * 16 + l15) * 32 + g * 8);
#pragma unroll
    for (int nt = 0; nt < 4; ++nt)
      b[nt] = *(const bf16x8*)(Bs + (wc * 64 + nt * 16 + l15) * 32 + g * 8);
#pragma unroll
    for (int mt = 0; mt < 2; ++mt)
#pragma unroll
      for (int nt = 0; nt < 4; ++nt)
        acc[mt][nt] = __builtin_amdgcn_mfma_f32_16x16x32_bf16(a[mt], b[nt], acc[mt][nt], 0, 0, 0);
  }

#pragma unroll
  for (int mt = 0; mt < 2; ++mt)
#pragma unroll
    for (int nt = 0; nt < 4; ++nt) {
      int col = colBase + wc * 64 + nt * 16 + l15;
      float bia = b_o[col];
#pragma unroll
      for (int r = 0; r < 4; ++r) {
        int row = rowBase + wr * 32 + mt * 16 + g * 4 + r;
        C[(((size_t)row) << 10) + col] = acc[mt][nt][r] + bia;
      }
    }
}

// ---------- flash attention (kv-split: 8 waves = 2 halves x 4 waves) ----------
// Grid (16, 32): 16 q-blocks of 128, 32 (b,h). 512 thr = 8 waves.
// Wave w: q rows (w&3)*32.., kv half h = w>>2 (tiles h*16 .. h*16+15).
// 4096 waves total -> 4 waves/SIMD (2x R12) with UNCHANGED per-CU staging
// volume (q-coverage per block stays 128; each tile staged once per block).
// Epilogue: partner waves have identical lane->(q,d) maps, so the online-
// softmax merge is lane-local after one LDS round-trip (overlaid on half-B's
// dead K/V buffers).
template <int KS4>
__device__ __forceinline__ void pv_step(const f32x16& sv, int hi, const u16* Vt, int l31,
                                        f32x16& o0, f32x16& o1) {
  constexpr int B = (KS4 & 1) * 8;
  u32x4 pd;
  pd[0] = cvtpk(sv[B + 0], sv[B + 1]);
  pd[1] = cvtpk(sv[B + 2], sv[B + 3]);
  pd[2] = cvtpk(sv[B + 4], sv[B + 5]);
  pd[3] = cvtpk(sv[B + 6], sv[B + 7]);
  bf16x8 pfrag = __builtin_bit_cast(bf16x8, pd);
  bf16x8 av0 = *(const bf16x8*)(Vt + lds_off(l31, 2 * KS4 + hi));
  bf16x8 av1 = *(const bf16x8*)(Vt + lds_off(32 + l31, 2 * KS4 + hi));
  o0 = __builtin_amdgcn_mfma_f32_32x32x16_bf16(av0, pfrag, o0, 0, 0, 0);
  o1 = __builtin_amdgcn_mfma_f32_32x32x16_bf16(av1, pfrag, o1, 0, 0, 0);
}

__global__ __launch_bounds__(512, 4)
void flash_attn(const u16* __restrict__ Qp, const u16* __restrict__ Kp,
                const u16* __restrict__ VT, u16* __restrict__ AO) {
  __shared__ __align__(16) u16 KB[2][2][64 * 64];   // [half][dbuf]
  __shared__ __align__(16) u16 VB[2][2][64 * 64];
  __shared__ float shML[2][256];

  const int tid = threadIdx.x;
  const int lane = tid & 63;
  const int w = tid >> 6;        // 0..7
  const int h = w >> 2;          // kv half
  const int wq = w & 3;          // q sub-block
  const int l31 = lane & 31;
  const int hi = lane >> 5;
  const int tid256 = tid & 255;

  // bijective XCD swizzle (nwg=512, 8 XCDs -> 64 contiguous wgs per XCD = 4 bh)
  const int flat = blockIdx.x + (blockIdx.y << 4);
  const int wgid = (flat & 7) * 64 + (flat >> 3);
  const int bh = wgid >> 4;
  const int qblk = wgid & 15;
  const int b = bh >> 4, hd = bh & 15;
  const int q = qblk * 128 + wq * 32 + l31;

  const size_t qrow = ((size_t)(b * 2048 + q)) << 10;
  const u16* Kbase = Kp + (((size_t)(b * 2048)) << 10) + hd * 64;
  const u16* Vbase = VT + (((size_t)(bh * 64)) << 11);

  // staging (per half): LDS dest linear, global source pre-swizzled (rule #21).
  const int sr = tid256 >> 3;
  const int sc = (tid256 & 7) ^ (sr & 7);

  auto stage = [&](int tt, int buf) {
    const int kv0 = tt * 64;
    gload16(Kbase + (((size_t)(kv0 + sr)) << 10) + sc * 8, &KB[h][buf][tid256 * 8]);
    gload16(Kbase + (((size_t)(kv0 + 32 + sr)) << 10) + sc * 8, &KB[h][buf][2048 + tid256 * 8]);
    gload16(Vbase + sr * 2048 + kv0 + sc * 8, &VB[h][buf][tid256 * 8]);
    gload16(Vbase + (32 + sr) * 2048 + kv0 + sc * 8, &VB[h][buf][2048 + tid256 * 8]);
  };

  stage(h * 16, 0);

  // Q fragments (B-operand): d = ks*16 + hi*8 + j
  bf16x8 qf[4];
#pragma unroll
  for (int ks = 0; ks < 4; ++ks)
    qf[ks] = *(const bf16x8*)(Qp + qrow + hd * 64 + ks * 16 + hi * 8);

  float m = -1e30f, l = 0.f;
  f32x16 o0, o1;
#pragma unroll
  for (int i = 0; i < 16; ++i) { o0[i] = 0.f; o1[i] = 0.f; }

  for (int lt = 0; lt < 16; ++lt) {
    const int cb = lt & 1;
    // single sync point: own-loads drained, then block rendezvous
    asm volatile("s_waitcnt vmcnt(0)" ::: "memory");
    __builtin_amdgcn_sched_barrier(0);
    __builtin_amdgcn_s_barrier();
    __builtin_amdgcn_sched_barrier(0);
    if (lt < 15) stage(h * 16 + lt + 1, cb ^ 1);

    const u16* Kt = &KB[h][cb][0];
    const u16* Vt = &VB[h][cb][0];

    // S^T tile: rows kv (two 32-subtiles), cols q
    f32x16 s0, s1;
#pragma unroll
    for (int i = 0; i < 16; ++i) { s0[i] = 0.f; s1[i] = 0.f; }
#pragma unroll
    for (int ks = 0; ks < 4; ++ks) {
      bf16x8 ak0 = *(const bf16x8*)(Kt + lds_off(l31, 2 * ks + hi));
      bf16x8 ak1 = *(const bf16x8*)(Kt + lds_off(32 + l31, 2 * ks + hi));
      s0 = __builtin_amdgcn_mfma_f32_32x32x16_bf16(ak0, qf[ks], s0, 0, 0, 0);
      s1 = __builtin_amdgcn_mfma_f32_32x32x16_bf16(ak1, qf[ks], s1, 0, 0, 0);
    }

    // in-lane max over the lane's 32 kv values (log2-domain scores)
    f32x16 mm;
#pragma unroll
    for (int i = 0; i < 16; ++i) mm[i] = fmaxf(s0[i], s1[i]);
#pragma unroll
    for (int i = 0; i < 8; ++i) mm[i] = fmaxf(mm[i], mm[i + 8]);
#pragma unroll
    for (int i = 0; i < 4; ++i) mm[i] = fmaxf(mm[i], mm[i + 4]);
    float pm = fmaxf(fmaxf(mm[0], mm[1]), fmaxf(mm[2], mm[3]));
    pm = fmaxf(pm, __shfl_xor(pm, 32));

    // defer-max (T13)
    if (!__all(pm - m <= 11.0f)) {
      float mn = fmaxf(m, pm);
      float fr = EXP2(m - mn);
      m = mn;
      l *= fr;
#pragma unroll
      for (int i = 0; i < 16; ++i) { o0[i] *= fr; o1[i] *= fr; }
    }

    // p = exp2(s - m)
#pragma unroll
    for (int i = 0; i < 16; ++i) {
      s0[i] = EXP2(s0[i] - m);
      s1[i] = EXP2(s1[i] - m);
    }
    // row sum
#pragma unroll
    for (int i = 0; i < 16; ++i) mm[i] = s0[i] + s1[i];
#pragma unroll
    for (int i = 0; i < 8; ++i) mm[i] += mm[i + 8];
#pragma unroll
    for (int i = 0; i < 4; ++i) mm[i] += mm[i + 4];
    float ps = (mm[0] + mm[1]) + (mm[2] + mm[3]);
    ps += __shfl_xor(ps, 32);
    l += ps;

    // PV: O^T += V'^T * P  (V' pi-permuted in memory; P from own regs)
    pv_step<0>(s0, hi, Vt, l31, o0, o1);
    pv_step<1>(s0, hi, Vt, l31, o0, o1);
    pv_step<2>(s1, hi, Vt, l31, o0, o1);
    pv_step<3>(s1, hi, Vt, l31, o0, o1);
  }

  // ---- combine the two kv-halves (lane-aligned: partner waves share lane maps)
  const int wl = wq * 64 + lane;
  float* shO0 = (float*)&KB[1][0][0];   // 16 KB: [16][256] (half-B K bufs, dead)
  float* shO1 = (float*)&VB[1][0][0];   // 16 KB: [16][256] (half-B V bufs, dead)
  if (h == 1) {
#pragma unroll
    for (int i = 0; i < 16; ++i) {
      shO0[i * 256 + wl] = o0[i];
      shO1[i * 256 + wl] = o1[i];
    }
    shML[0][wl] = m;
    shML[1][wl] = l;
  }
  __syncthreads();
  if (h == 0) {
    float mb = shML[0][wl], lb = shML[1][wl];
    float M = fmaxf(m, mb);
    float f0 = EXP2(m - M), f1 = EXP2(mb - M);
    float linv = 1.0f / (l * f0 + lb * f1);
#pragma unroll
    for (int i = 0; i < 16; ++i) {
      o0[i] = o0[i] * f0 + shO0[i * 256 + wl] * f1;
      o1[i] = o1[i] * f0 + shO1[i * 256 + wl] * f1;
    }
#pragma unroll
    for (int dt = 0; dt < 2; ++dt) {
      const f32x16& oo = dt ? o1 : o0;
#pragma unroll
      for (int g = 0; g < 4; ++g) {
        u16x4 pk;
#pragma unroll
        for (int r = 0; r < 4; ++r) pk[r] = f2bf(oo[g * 4 + r] * linv);
        const int d = dt * 32 + g * 8 + hi * 4;
        *(u16x4*)(AO + qrow + hd * 64 + d) = pk;
      }
    }
  }
}

// ---------- launch ----------
extern "C" void kernel_launch(void* const* d_in, const int* in_sizes, int n_in,
                              void* d_out, int out_size, void* d_ws, size_t ws_size,
                              hipStream_t stream) {
  const float* q   = (const float*)d_in[1];
  const float* k   = (const float*)d_in[2];
  const float* v   = (const float*)d_in[3];
  const float* w_q = (const float*)d_in[5];
  const float* b_q = (const float*)d_in[6];
  const float* w_k = (const float*)d_in[7];
  const float* b_k = (const float*)d_in[8];
  const float* w_o = (const float*)d_in[11];
  const float* b_o = (const float*)d_in[12];
  float* out = (float*)d_out;

  u16* qb  = (u16*)d_ws;
  u16* kb  = qb  + 4194304;
  u16* vb  = kb  + 4194304;
  u16* wqb = vb  + 4194304;
  u16* wkb = wqb + 1048576;
  u16* wob = wkb + 1048576;
  u16* Qp  = wob + 1048576;
  u16* Kp  = Qp  + 4194304;
  u16* VTp = Kp  + 4194304;
  u16* AO  = qb;  // alias: qb dead after proj_gemm

  cvt_kernel<<<dim3(512, 6, 1), 256, 0, stream>>>(
      q, qb, 524288, k, kb, 524288, v, vb, 524288,
      w_q, wqb, 131072, w_k, wkb, 131072, w_o, wob, 131072);

  proj_gemm<<<dim3(32, 8, 3), 256, 0, stream>>>(qb, kb, vb, wqb, wkb, b_q, b_k, Qp, Kp, VTp);

  flash_attn<<<dim3(16, 32, 1), 512, 0, stream>>>(Qp, Kp, VTp, AO);

  out_gemm<<<dim3(64, 8, 1), 256, 0, stream>>>(AO, wob, b_o, out);
}